// Round 9
// baseline (133.179 us; speedup 1.0000x reference)
//
#include <hip/hip_runtime.h>
#include <math.h>

// Problem constants (fixed by setup_inputs)
#define NWORDS 8192
#define LW     24
#define VOC    128
#define DIM    512
#define NH     8
#define DKH    64
#define GNAMES 2048
#define F2     256

// stage-1 fused output layout (floats): [EQ 65536 | EK 65536 | EV 65536 | WF 262144]
#define S1_LEN 458752
#define H1OFF  1048576   // 2048*512, stride between NP@WF partials

// =================== double-buffered 64x64 fp32 GEMM body ====================
// 256 threads, BK=16, 4x4 register tile, one barrier per K-step.
// K_ is used as lda, N_ as ldb only.
#define GEMM_BODY(A_, B_, K_, N_, m0_, n0_, kbeg_, kchunk_)                         \
  __shared__ float As[2][16][68];                                                   \
  __shared__ float Bs[2][16][68];                                                   \
  const int t = threadIdx.x, tx = t & 15, ty = t >> 4;                              \
  float acc[4][4] = {};                                                             \
  float ra[4], rb[4];                                                               \
  _Pragma("unroll")                                                                 \
  for (int i = 0; i < 4; ++i) { int idx = t + 256 * i;                              \
    ra[i] = A_[(size_t)(m0_ + (idx >> 4)) * K_ + kbeg_ + (idx & 15)]; }             \
  _Pragma("unroll")                                                                 \
  for (int i = 0; i < 4; ++i) { int idx = t + 256 * i;                              \
    rb[i] = B_[(size_t)(kbeg_ + (idx >> 6)) * N_ + n0_ + (idx & 63)]; }             \
  _Pragma("unroll")                                                                 \
  for (int i = 0; i < 4; ++i) { int idx = t + 256 * i; As[0][idx & 15][idx >> 4] = ra[i]; } \
  _Pragma("unroll")                                                                 \
  for (int i = 0; i < 4; ++i) { int idx = t + 256 * i; Bs[0][idx >> 6][idx & 63] = rb[i]; } \
  __syncthreads();                                                                  \
  int buf = 0;                                                                      \
  for (int k0 = kbeg_; k0 < kbeg_ + kchunk_; k0 += 16) {                            \
    const bool more = (k0 + 16 < kbeg_ + kchunk_);                                  \
    if (more) {                                                                     \
      _Pragma("unroll")                                                             \
      for (int i = 0; i < 4; ++i) { int idx = t + 256 * i;                          \
        ra[i] = A_[(size_t)(m0_ + (idx >> 4)) * K_ + (k0 + 16) + (idx & 15)]; }     \
      _Pragma("unroll")                                                             \
      for (int i = 0; i < 4; ++i) { int idx = t + 256 * i;                          \
        rb[i] = B_[(size_t)(k0 + 16 + (idx >> 6)) * N_ + n0_ + (idx & 63)]; }       \
    }                                                                               \
    _Pragma("unroll")                                                               \
    for (int k = 0; k < 16; ++k) {                                                  \
      float a[4], b[4];                                                             \
      _Pragma("unroll")                                                             \
      for (int i = 0; i < 4; ++i) a[i] = As[buf][k][ty * 4 + i];                    \
      _Pragma("unroll")                                                             \
      for (int j = 0; j < 4; ++j) b[j] = Bs[buf][k][tx * 4 + j];                    \
      _Pragma("unroll")                                                             \
      for (int i = 0; i < 4; ++i)                                                   \
        _Pragma("unroll")                                                           \
        for (int j = 0; j < 4; ++j) acc[i][j] += a[i] * b[j];                       \
    }                                                                               \
    if (more) {                                                                     \
      _Pragma("unroll")                                                             \
      for (int i = 0; i < 4; ++i) { int idx = t + 256 * i; As[buf ^ 1][idx & 15][idx >> 4] = ra[i]; } \
      _Pragma("unroll")                                                             \
      for (int i = 0; i < 4; ++i) { int idx = t + 256 * i; Bs[buf ^ 1][idx >> 6][idx & 63] = rb[i]; } \
      __syncthreads();                                                              \
      buf ^= 1;                                                                     \
    }                                                                               \
  }

// ---- stage-1 fused GEMM: EQ/EK/EV (128x512) + WF=Wo@W1 (512x512), all K=512 ----
template<int NSPLIT>
__global__ __launch_bounds__(256) void k_stage1(const float* __restrict__ emb,
                                                const float* __restrict__ Wq,
                                                const float* __restrict__ Wk,
                                                const float* __restrict__ Wv,
                                                const float* __restrict__ Wo,
                                                const float* __restrict__ W1,
                                                float* __restrict__ P) {
  const int tid = blockIdx.x, s = blockIdx.y;
  const float *A, *B;
  int coff, m0, n0;
  if (tid < 48) {
    const int g = tid >> 4, mt = tid & 15;
    A = emb;
    B = (g == 0) ? Wq : ((g == 1) ? Wk : Wv);
    coff = g * 65536;
    m0 = (mt >> 3) * 64; n0 = (mt & 7) * 64;
  } else {
    const int id = tid - 48;
    A = Wo; B = W1; coff = 3 * 65536;
    m0 = (id >> 3) * 64; n0 = (id & 7) * 64;
  }
  const int kchunk = 512 / NSPLIT, kbeg = s * kchunk;
  GEMM_BODY(A, B, 512, 512, m0, n0, kbeg, kchunk)
  float* Cp = P + (size_t)s * S1_LEN + coff;
  #pragma unroll
  for (int i = 0; i < 4; ++i) {
    float4 v = make_float4(acc[i][0], acc[i][1], acc[i][2], acc[i][3]);
    *(float4*)&Cp[(size_t)(m0 + ty * 4 + i) * 512 + n0 + tx * 4] = v;
  }
}

// ---- generic GEMM: C = A@B partials over gridDim.z ----
template<int ACT>
__global__ __launch_bounds__(256) void k_gemm64(const float* __restrict__ A,
                                                const float* __restrict__ B,
                                                float* __restrict__ C,
                                                int M, int N, int K, int kchunk) {
  const int m0 = blockIdx.y * 64, n0 = blockIdx.x * 64;
  const int kbeg = blockIdx.z * kchunk;
  GEMM_BODY(A, B, K, N, m0, n0, kbeg, kchunk)
  float* Cp = C + (size_t)blockIdx.z * M * N;
  #pragma unroll
  for (int i = 0; i < 4; ++i) {
    float4 v = make_float4(acc[i][0], acc[i][1], acc[i][2], acc[i][3]);
    if (ACT) { v.x = tanhf(v.x); v.y = tanhf(v.y); v.z = tanhf(v.z); v.w = tanhf(v.w); }
    *(float4*)&Cp[(size_t)(m0 + ty * 4 + i) * N + n0 + tx * 4] = v;
  }
}

// ---- tail GEMM: A = tanh(sum of 4 NP@WF partials), B = W2, C = out partials ----
__global__ __launch_bounds__(256) void k_gemm_tail(const float* __restrict__ P,
                                                   const float* __restrict__ B,
                                                   float* __restrict__ C,
                                                   int kchunk) {
  const int N = 256, K = 512;
  __shared__ float As[2][16][68];
  __shared__ float Bs[2][16][68];
  const int t = threadIdx.x, tx = t & 15, ty = t >> 4;
  const int m0 = blockIdx.y * 64, n0 = blockIdx.x * 64;
  const int kbeg = blockIdx.z * kchunk;
  float acc[4][4] = {};
  float ra[4], rb[4];
  #pragma unroll
  for (int i = 0; i < 4; ++i) {
    int idx = t + 256 * i;
    size_t off = (size_t)(m0 + (idx >> 4)) * K + kbeg + (idx & 15);
    ra[i] = tanhf(P[off] + P[off + H1OFF] + P[off + 2 * H1OFF] + P[off + 3 * H1OFF]);
  }
  #pragma unroll
  for (int i = 0; i < 4; ++i) {
    int idx = t + 256 * i;
    rb[i] = B[(size_t)(kbeg + (idx >> 6)) * N + n0 + (idx & 63)];
  }
  #pragma unroll
  for (int i = 0; i < 4; ++i) { int idx = t + 256 * i; As[0][idx & 15][idx >> 4] = ra[i]; }
  #pragma unroll
  for (int i = 0; i < 4; ++i) { int idx = t + 256 * i; Bs[0][idx >> 6][idx & 63] = rb[i]; }
  __syncthreads();
  int buf = 0;
  for (int k0 = kbeg; k0 < kbeg + kchunk; k0 += 16) {
    const bool more = (k0 + 16 < kbeg + kchunk);
    if (more) {
      #pragma unroll
      for (int i = 0; i < 4; ++i) {
        int idx = t + 256 * i;
        size_t off = (size_t)(m0 + (idx >> 4)) * K + (k0 + 16) + (idx & 15);
        ra[i] = tanhf(P[off] + P[off + H1OFF] + P[off + 2 * H1OFF] + P[off + 3 * H1OFF]);
      }
      #pragma unroll
      for (int i = 0; i < 4; ++i) {
        int idx = t + 256 * i;
        rb[i] = B[(size_t)(k0 + 16 + (idx >> 6)) * N + n0 + (idx & 63)];
      }
    }
    #pragma unroll
    for (int k = 0; k < 16; ++k) {
      float a[4], b[4];
      #pragma unroll
      for (int i = 0; i < 4; ++i) a[i] = As[buf][k][ty * 4 + i];
      #pragma unroll
      for (int j = 0; j < 4; ++j) b[j] = Bs[buf][k][tx * 4 + j];
      #pragma unroll
      for (int i = 0; i < 4; ++i)
        #pragma unroll
        for (int j = 0; j < 4; ++j) acc[i][j] += a[i] * b[j];
    }
    if (more) {
      #pragma unroll
      for (int i = 0; i < 4; ++i) { int idx = t + 256 * i; As[buf ^ 1][idx & 15][idx >> 4] = ra[i]; }
      #pragma unroll
      for (int i = 0; i < 4; ++i) { int idx = t + 256 * i; Bs[buf ^ 1][idx >> 6][idx & 63] = rb[i]; }
      __syncthreads();
      buf ^= 1;
    }
  }
  float* Cp = C + (size_t)blockIdx.z * (GNAMES * F2);
  #pragma unroll
  for (int i = 0; i < 4; ++i) {
    float4 v = make_float4(acc[i][0], acc[i][1], acc[i][2], acc[i][3]);
    *(float4*)&Cp[(size_t)(m0 + ty * 4 + i) * N + n0 + tx * 4] = v;
  }
}

// ---- sum S partial buffers, optional tanh ----
template<int ACT, int S>
__global__ __launch_bounds__(256) void k_reduce(const float* __restrict__ P,
                                                float* __restrict__ O,
                                                int len4, int stride4) {
  const int i = blockIdx.x * 256 + threadIdx.x;
  if (i >= len4) return;
  const float4* P4 = (const float4*)P;
  float4 a = P4[i];
  #pragma unroll
  for (int s = 1; s < S; ++s) {
    float4 b = P4[(size_t)s * stride4 + i];
    a.x += b.x; a.y += b.y; a.z += b.z; a.w += b.w;
  }
  if (ACT) { a.x = tanhf(a.x); a.y = tanhf(a.y); a.z = tanhf(a.z); a.w = tanhf(a.w); }
  ((float4*)O)[i] = a;
}

// ---- exp(qk) table, zeroed on pad rows/cols: ETAB[c1][c2][h] ----
__global__ __launch_bounds__(128) void k_qk_tab(const float* __restrict__ EQ,
                                                const float* __restrict__ EK,
                                                float* __restrict__ etab) {
  const int c1 = blockIdx.x, h = blockIdx.y, c2 = threadIdx.x;
  __shared__ float qrow[DKH];
  if (threadIdx.x < DKH) qrow[threadIdx.x] = EQ[c1 * DIM + h * DKH + threadIdx.x];
  __syncthreads();
  const float* krow = EK + c2 * DIM + h * DKH;
  float acc = 0.f;
  #pragma unroll
  for (int d = 0; d < DKH; ++d) acc += qrow[d] * krow[d];
  float e = (c1 != 0 && c2 != 0) ? __expf(acc * 0.125f) : 0.f;
  etab[((size_t)c1 * VOC + c2) * NH + h] = e;
}

// ---- fused: in-block offsets + attention-mass histogram + name-pool ----
// Block = name, 256 thr = 4 waves, wave = word (round-8 proven core).
// Prologue: block-local prefix sum over n_words -> (o0, nw); then the
// register-cached two-pass softmax histogram into bins[c][h]; epilogue:
// NP[g][j] = invn * sum_c bins[c][h(j)]*EV[c][j]  (EV is L2-resident).
__global__ __launch_bounds__(256) void k_binsnp(const int* __restrict__ inputs,
                                                const int* __restrict__ nwords,
                                                const float* __restrict__ etab,
                                                const float* __restrict__ EV,
                                                float* __restrict__ NP) {
  const int g = blockIdx.x, t = threadIdx.x;
  const int wv = t >> 6, l = t & 63;
  const int h = l & 7, qg = l >> 3;
  __shared__ float bins[VOC * NH];  // [c][h], 4 KB
  __shared__ int wred[4];
  __shared__ int sh_nwg;

  for (int i = t; i < VOC * NH; i += 256) bins[i] = 0.f;
  // in-block exclusive prefix: o0 = sum_{i<g} n_words[i], nw = n_words[g]
  int partial = 0;
  for (int i = t; i < GNAMES; i += 256) {
    int v = nwords[i];
    partial += (i < g) ? v : 0;
    if (i == g) sh_nwg = v;  // unique writer
  }
  #pragma unroll
  for (int d = 1; d < 64; d <<= 1) partial += __shfl_xor(partial, d);
  if (l == 0) wred[wv] = partial;
  __syncthreads();
  const int nw = sh_nwg;
  const int o0 = wred[0] + wred[1] + wred[2] + wred[3];

  for (int wrel = wv; wrel < nw; wrel += 4) {
    const int wi = o0 + wrel;
    int c_l = (l < LW) ? inputs[(size_t)wi * LW + l] : 0;
    unsigned long long mk = __ballot(c_l != 0);
    int cnt = __popcll(mk);
    float invc = cnt ? 1.f / (float)cnt : 0.f;

    int cq0 = __shfl(c_l, qg);
    int cq1 = __shfl(c_l, qg + 8);
    int cq2 = __shfl(c_l, qg + 16);
    const float* b0 = etab + (cq0 << 10) + h;
    const float* b1 = etab + (cq1 << 10) + h;
    const float* b2 = etab + (cq2 << 10) + h;

    // pass 1: gather rows into registers, accumulate denominators
    float r0[LW], r1[LW], r2[LW];
    float d0 = 0.f, d1 = 0.f, d2 = 0.f;
    #pragma unroll
    for (int kp = 0; kp < LW; ++kp) {
      int o = __shfl(c_l, kp) << 3;
      r0[kp] = b0[o]; r1[kp] = b1[o]; r2[kp] = b2[o];
      d0 += r0[kp]; d1 += r1[kp]; d2 += r2[kp];
    }
    float i0 = cq0 ? invc / d0 : 0.f;
    float i1 = cq1 ? invc / d1 : 0.f;
    float i2 = cq2 ? invc / d2 : 0.f;

    // pass 2: register-only weighting, q-reduce, scatter to char bins
    #pragma unroll
    for (int kp = 0; kp < LW; ++kp) {
      int ck = __shfl(c_l, kp);   // wave-uniform
      if (ck) {
        float v = r0[kp] * i0 + r1[kp] * i1 + r2[kp] * i2;
        v += __shfl_xor(v, 8);
        v += __shfl_xor(v, 16);
        v += __shfl_xor(v, 32);
        if (qg == 0) atomicAdd(&bins[(ck << 3) + h], v);
      }
    }
  }
  __syncthreads();

  // epilogue: NP[g][2t..2t+1] = invn * sum_c bins[c][h2] * EV[c][2t..2t+1]
  const float invn = nw ? 1.f / (float)nw : 0.f;
  const int h2 = t >> 5;                 // h of column j = 2t
  const float2* EV2 = (const float2*)EV;
  float sx = 0.f, sy = 0.f;
  #pragma unroll 4
  for (int c = 0; c < VOC; ++c) {
    float w = bins[(c << 3) + h2];
    float2 ev = EV2[c * 256 + t];
    sx += w * ev.x; sy += w * ev.y;
  }
  float2 r; r.x = sx * invn; r.y = sy * invn;
  ((float2*)NP)[(size_t)g * 256 + t] = r;
}

extern "C" void kernel_launch(void* const* d_in, const int* in_sizes, int n_in,
                              void* d_out, int out_size, void* d_ws, size_t ws_size,
                              hipStream_t stream) {
  const int*   inputs  = (const int*)d_in[0];
  const int*   n_words = (const int*)d_in[1];
  const float* emb     = (const float*)d_in[3];
  const float* Wq      = (const float*)d_in[4];
  const float* Wk      = (const float*)d_in[5];
  const float* Wv      = (const float*)d_in[6];
  const float* Wo      = (const float*)d_in[7];
  const float* W1      = (const float*)d_in[8];
  const float* W2      = (const float*)d_in[9];
  float* out = (float*)d_out;

  // workspace layout (floats), ~31.7 MB (d_ws is 256 MB per poison-fill size)
  float* ws   = (float*)d_ws;
  float* ES   = ws;                     // 458752: [EQ|EK|EV|WF]
  float* BIG  = ws + 458752;            // 4194304: stage1 partials, then NP@WF partials
  float* TAB  = ws + 4653056;           // 131072: exp table [c1][c2][h]
  float* NP   = ws + 4784128;           // 2048*512
  float* OUTP = ws + 5832704;           // 4 x 2048*256 out partials

  // stage-1 fused GEMMs, split-K=4 -> 448 blocks
  k_stage1<4><<<dim3(112, 4), 256, 0, stream>>>(emb, Wq, Wk, Wv, Wo, W1, BIG);
  k_reduce<0, 4><<<S1_LEN / 4 / 256, 256, 0, stream>>>(BIG, ES, S1_LEN / 4, S1_LEN / 4);
  // exp(qk) table from EQ, EK (pad rows/cols zeroed)
  k_qk_tab<<<dim3(VOC, NH), 128, 0, stream>>>(ES, ES + 65536, TAB);
  // fused offsets + histogram + name-pool -> NP
  k_binsnp<<<GNAMES, 256, 0, stream>>>(inputs, n_words, TAB, ES + 131072, NP);
  // NP @ WF, split-K=4 -> partials in BIG (stage1 partials dead by now)
  k_gemm64<0><<<dim3(8, 32, 4), 256, 0, stream>>>(NP, ES + 196608, BIG, 2048, 512, 512, 128);
  // out_partials = tanh(sum BIG partials) @ W2, split-K=4
  k_gemm_tail<<<dim3(4, 32, 4), 256, 0, stream>>>(BIG, W2, OUTP, 128);
  // out = tanh(sum out_partials)
  k_reduce<1, 4><<<(GNAMES * F2) / 4 / 256, 256, 0, stream>>>(OUTP, out, (GNAMES * F2) / 4, (GNAMES * F2) / 4);
}

// Round 10
// 106.989 us; speedup vs baseline: 1.2448x; 1.2448x over previous
//
#include <hip/hip_runtime.h>
#include <math.h>

// Problem constants (fixed by setup_inputs)
#define NWORDS 8192
#define LW     24
#define VOC    128
#define DIM    512
#define NH     8
#define DKH    64
#define GNAMES 2048
#define F2     256

// stage-1 fused output layout (floats): [EQ 65536 | EK 65536 | EV 65536 | WF 262144]
#define S1_LEN 458752
#define H1OFF  1048576   // 2048*512, stride between NP@WF partials

// =================== double-buffered 64x64 fp32 GEMM body ====================
// 256 threads, BK=16, 4x4 register tile, one barrier per K-step.
// K_ is used as lda, N_ as ldb only.
#define GEMM_BODY(A_, B_, K_, N_, m0_, n0_, kbeg_, kchunk_)                         \
  __shared__ float As[2][16][68];                                                   \
  __shared__ float Bs[2][16][68];                                                   \
  const int t = threadIdx.x, tx = t & 15, ty = t >> 4;                              \
  float acc[4][4] = {};                                                             \
  float ra[4], rb[4];                                                               \
  _Pragma("unroll")                                                                 \
  for (int i = 0; i < 4; ++i) { int idx = t + 256 * i;                              \
    ra[i] = A_[(size_t)(m0_ + (idx >> 4)) * K_ + kbeg_ + (idx & 15)]; }             \
  _Pragma("unroll")                                                                 \
  for (int i = 0; i < 4; ++i) { int idx = t + 256 * i;                              \
    rb[i] = B_[(size_t)(kbeg_ + (idx >> 6)) * N_ + n0_ + (idx & 63)]; }             \
  _Pragma("unroll")                                                                 \
  for (int i = 0; i < 4; ++i) { int idx = t + 256 * i; As[0][idx & 15][idx >> 4] = ra[i]; } \
  _Pragma("unroll")                                                                 \
  for (int i = 0; i < 4; ++i) { int idx = t + 256 * i; Bs[0][idx >> 6][idx & 63] = rb[i]; } \
  __syncthreads();                                                                  \
  int buf = 0;                                                                      \
  for (int k0 = kbeg_; k0 < kbeg_ + kchunk_; k0 += 16) {                            \
    const bool more = (k0 + 16 < kbeg_ + kchunk_);                                  \
    if (more) {                                                                     \
      _Pragma("unroll")                                                             \
      for (int i = 0; i < 4; ++i) { int idx = t + 256 * i;                          \
        ra[i] = A_[(size_t)(m0_ + (idx >> 4)) * K_ + (k0 + 16) + (idx & 15)]; }     \
      _Pragma("unroll")                                                             \
      for (int i = 0; i < 4; ++i) { int idx = t + 256 * i;                          \
        rb[i] = B_[(size_t)(k0 + 16 + (idx >> 6)) * N_ + n0_ + (idx & 63)]; }       \
    }                                                                               \
    _Pragma("unroll")                                                               \
    for (int k = 0; k < 16; ++k) {                                                  \
      float a[4], b[4];                                                             \
      _Pragma("unroll")                                                             \
      for (int i = 0; i < 4; ++i) a[i] = As[buf][k][ty * 4 + i];                    \
      _Pragma("unroll")                                                             \
      for (int j = 0; j < 4; ++j) b[j] = Bs[buf][k][tx * 4 + j];                    \
      _Pragma("unroll")                                                             \
      for (int i = 0; i < 4; ++i)                                                   \
        _Pragma("unroll")                                                           \
        for (int j = 0; j < 4; ++j) acc[i][j] += a[i] * b[j];                       \
    }                                                                               \
    if (more) {                                                                     \
      _Pragma("unroll")                                                             \
      for (int i = 0; i < 4; ++i) { int idx = t + 256 * i; As[buf ^ 1][idx & 15][idx >> 4] = ra[i]; } \
      _Pragma("unroll")                                                             \
      for (int i = 0; i < 4; ++i) { int idx = t + 256 * i; Bs[buf ^ 1][idx >> 6][idx & 63] = rb[i]; } \
      __syncthreads();                                                              \
      buf ^= 1;                                                                     \
    }                                                                               \
  }

// ---- stage-1 fused GEMM: EQ/EK/EV (128x512) + WF=Wo@W1 (512x512), all K=512 ----
template<int NSPLIT>
__global__ __launch_bounds__(256) void k_stage1(const float* __restrict__ emb,
                                                const float* __restrict__ Wq,
                                                const float* __restrict__ Wk,
                                                const float* __restrict__ Wv,
                                                const float* __restrict__ Wo,
                                                const float* __restrict__ W1,
                                                float* __restrict__ P) {
  const int tid = blockIdx.x, s = blockIdx.y;
  const float *A, *B;
  int coff, m0, n0;
  if (tid < 48) {
    const int g = tid >> 4, mt = tid & 15;
    A = emb;
    B = (g == 0) ? Wq : ((g == 1) ? Wk : Wv);
    coff = g * 65536;
    m0 = (mt >> 3) * 64; n0 = (mt & 7) * 64;
  } else {
    const int id = tid - 48;
    A = Wo; B = W1; coff = 3 * 65536;
    m0 = (id >> 3) * 64; n0 = (id & 7) * 64;
  }
  const int kchunk = 512 / NSPLIT, kbeg = s * kchunk;
  GEMM_BODY(A, B, 512, 512, m0, n0, kbeg, kchunk)
  float* Cp = P + (size_t)s * S1_LEN + coff;
  #pragma unroll
  for (int i = 0; i < 4; ++i) {
    float4 v = make_float4(acc[i][0], acc[i][1], acc[i][2], acc[i][3]);
    *(float4*)&Cp[(size_t)(m0 + ty * 4 + i) * 512 + n0 + tx * 4] = v;
  }
}

// ---- generic GEMM: C = A@B partials over gridDim.z ----
template<int ACT>
__global__ __launch_bounds__(256) void k_gemm64(const float* __restrict__ A,
                                                const float* __restrict__ B,
                                                float* __restrict__ C,
                                                int M, int N, int K, int kchunk) {
  const int m0 = blockIdx.y * 64, n0 = blockIdx.x * 64;
  const int kbeg = blockIdx.z * kchunk;
  GEMM_BODY(A, B, K, N, m0, n0, kbeg, kchunk)
  float* Cp = C + (size_t)blockIdx.z * M * N;
  #pragma unroll
  for (int i = 0; i < 4; ++i) {
    float4 v = make_float4(acc[i][0], acc[i][1], acc[i][2], acc[i][3]);
    if (ACT) { v.x = tanhf(v.x); v.y = tanhf(v.y); v.z = tanhf(v.z); v.w = tanhf(v.w); }
    *(float4*)&Cp[(size_t)(m0 + ty * 4 + i) * N + n0 + tx * 4] = v;
  }
}

// ---- name-pool GEMM: NP[m, h*64+n] = sum_c Wn[m][h*128+c] * EV[c][h*64+n] ----
__global__ __launch_bounds__(256) void k_npool(const float* __restrict__ Wn,
                                               const float* __restrict__ EV,
                                               float* __restrict__ NP) {
  const int m0 = blockIdx.x * 64, h = blockIdx.y;
  const float* A2 = Wn + (size_t)m0 * 1024 + h * 128;   // lda 1024
  const float* B2 = EV + h * 64;                        // ldb 512
  GEMM_BODY(A2, B2, 1024, 512, 0, 0, 0, 128)
  #pragma unroll
  for (int i = 0; i < 4; ++i) {
    float4 v = make_float4(acc[i][0], acc[i][1], acc[i][2], acc[i][3]);
    *(float4*)&NP[(size_t)(m0 + ty * 4 + i) * 512 + h * 64 + tx * 4] = v;
  }
}

// ---- tail GEMM: A = tanh(sum of 4 NP@WF partials), B = W2, C = out partials ----
__global__ __launch_bounds__(256) void k_gemm_tail(const float* __restrict__ P,
                                                   const float* __restrict__ B,
                                                   float* __restrict__ C,
                                                   int kchunk) {
  const int N = 256, K = 512;
  __shared__ float As[2][16][68];
  __shared__ float Bs[2][16][68];
  const int t = threadIdx.x, tx = t & 15, ty = t >> 4;
  const int m0 = blockIdx.y * 64, n0 = blockIdx.x * 64;
  const int kbeg = blockIdx.z * kchunk;
  float acc[4][4] = {};
  float ra[4], rb[4];
  #pragma unroll
  for (int i = 0; i < 4; ++i) {
    int idx = t + 256 * i;
    size_t off = (size_t)(m0 + (idx >> 4)) * K + kbeg + (idx & 15);
    ra[i] = tanhf(P[off] + P[off + H1OFF] + P[off + 2 * H1OFF] + P[off + 3 * H1OFF]);
  }
  #pragma unroll
  for (int i = 0; i < 4; ++i) {
    int idx = t + 256 * i;
    rb[i] = B[(size_t)(kbeg + (idx >> 6)) * N + n0 + (idx & 63)];
  }
  #pragma unroll
  for (int i = 0; i < 4; ++i) { int idx = t + 256 * i; As[0][idx & 15][idx >> 4] = ra[i]; }
  #pragma unroll
  for (int i = 0; i < 4; ++i) { int idx = t + 256 * i; Bs[0][idx >> 6][idx & 63] = rb[i]; }
  __syncthreads();
  int buf = 0;
  for (int k0 = kbeg; k0 < kbeg + kchunk; k0 += 16) {
    const bool more = (k0 + 16 < kbeg + kchunk);
    if (more) {
      #pragma unroll
      for (int i = 0; i < 4; ++i) {
        int idx = t + 256 * i;
        size_t off = (size_t)(m0 + (idx >> 4)) * K + (k0 + 16) + (idx & 15);
        ra[i] = tanhf(P[off] + P[off + H1OFF] + P[off + 2 * H1OFF] + P[off + 3 * H1OFF]);
      }
      #pragma unroll
      for (int i = 0; i < 4; ++i) {
        int idx = t + 256 * i;
        rb[i] = B[(size_t)(k0 + 16 + (idx >> 6)) * N + n0 + (idx & 63)];
      }
    }
    #pragma unroll
    for (int k = 0; k < 16; ++k) {
      float a[4], b[4];
      #pragma unroll
      for (int i = 0; i < 4; ++i) a[i] = As[buf][k][ty * 4 + i];
      #pragma unroll
      for (int j = 0; j < 4; ++j) b[j] = Bs[buf][k][tx * 4 + j];
      #pragma unroll
      for (int i = 0; i < 4; ++i)
        #pragma unroll
        for (int j = 0; j < 4; ++j) acc[i][j] += a[i] * b[j];
    }
    if (more) {
      #pragma unroll
      for (int i = 0; i < 4; ++i) { int idx = t + 256 * i; As[buf ^ 1][idx & 15][idx >> 4] = ra[i]; }
      #pragma unroll
      for (int i = 0; i < 4; ++i) { int idx = t + 256 * i; Bs[buf ^ 1][idx >> 6][idx & 63] = rb[i]; }
      __syncthreads();
      buf ^= 1;
    }
  }
  float* Cp = C + (size_t)blockIdx.z * (GNAMES * F2);
  #pragma unroll
  for (int i = 0; i < 4; ++i) {
    float4 v = make_float4(acc[i][0], acc[i][1], acc[i][2], acc[i][3]);
    *(float4*)&Cp[(size_t)(m0 + ty * 4 + i) * N + n0 + tx * 4] = v;
  }
}

// ---- sum S partial buffers, optional tanh ----
template<int ACT, int S>
__global__ __launch_bounds__(256) void k_reduce(const float* __restrict__ P,
                                                float* __restrict__ O,
                                                int len4, int stride4) {
  const int i = blockIdx.x * 256 + threadIdx.x;
  if (i >= len4) return;
  const float4* P4 = (const float4*)P;
  float4 a = P4[i];
  #pragma unroll
  for (int s = 1; s < S; ++s) {
    float4 b = P4[(size_t)s * stride4 + i];
    a.x += b.x; a.y += b.y; a.z += b.z; a.w += b.w;
  }
  if (ACT) { a.x = tanhf(a.x); a.y = tanhf(a.y); a.z = tanhf(a.z); a.w = tanhf(a.w); }
  ((float4*)O)[i] = a;
}

// ---- exp(qk) table, zeroed on pad rows/cols: ETAB[c1][c2][h] ----
__global__ __launch_bounds__(128) void k_qk_tab(const float* __restrict__ EQ,
                                                const float* __restrict__ EK,
                                                float* __restrict__ etab) {
  const int c1 = blockIdx.x, h = blockIdx.y, c2 = threadIdx.x;
  __shared__ float qrow[DKH];
  if (threadIdx.x < DKH) qrow[threadIdx.x] = EQ[c1 * DIM + h * DKH + threadIdx.x];
  __syncthreads();
  const float* krow = EK + c2 * DIM + h * DKH;
  float acc = 0.f;
  #pragma unroll
  for (int d = 0; d < DKH; ++d) acc += qrow[d] * krow[d];
  float e = (c1 != 0 && c2 != 0) ? __expf(acc * 0.125f) : 0.f;
  etab[((size_t)c1 * VOC + c2) * NH + h] = e;
}

// ---- fused: in-block offsets + attention-mass histogram -> Wn[g][h][c] ----
// Block = name, 256 thr = 4 waves, wave = word (round-8 proven core).
// Prologue: block-local prefix sum over n_words -> (o0, nw). Histogram:
// register-cached two-pass softmax into bins[c][h] via LDS atomics.
// Epilogue writes only the 4KB Wn slice; the EV contraction stays in the
// tiled k_npool GEMM (round-9 lesson: fusing it destroys EV reuse).
__global__ __launch_bounds__(256) void k_bins(const int* __restrict__ inputs,
                                              const int* __restrict__ nwords,
                                              const float* __restrict__ etab,
                                              float* __restrict__ Wn) {
  const int g = blockIdx.x, t = threadIdx.x;
  const int wv = t >> 6, l = t & 63;
  const int h = l & 7, qg = l >> 3;
  __shared__ float bins[VOC * NH];  // [c][h], 4 KB
  __shared__ int wred[4];
  __shared__ int sh_nwg;

  for (int i = t; i < VOC * NH; i += 256) bins[i] = 0.f;
  // in-block exclusive prefix: o0 = sum_{i<g} n_words[i], nw = n_words[g]
  int partial = 0;
  for (int i = t; i < GNAMES; i += 256) {
    int v = nwords[i];
    partial += (i < g) ? v : 0;
    if (i == g) sh_nwg = v;  // unique writer
  }
  #pragma unroll
  for (int d = 1; d < 64; d <<= 1) partial += __shfl_xor(partial, d);
  if (l == 0) wred[wv] = partial;
  __syncthreads();
  const int nw = sh_nwg;
  const int o0 = wred[0] + wred[1] + wred[2] + wred[3];

  for (int wrel = wv; wrel < nw; wrel += 4) {
    const int wi = o0 + wrel;
    int c_l = (l < LW) ? inputs[(size_t)wi * LW + l] : 0;
    unsigned long long mk = __ballot(c_l != 0);
    int cnt = __popcll(mk);
    float invc = cnt ? 1.f / (float)cnt : 0.f;

    int cq0 = __shfl(c_l, qg);
    int cq1 = __shfl(c_l, qg + 8);
    int cq2 = __shfl(c_l, qg + 16);
    const float* b0 = etab + (cq0 << 10) + h;
    const float* b1 = etab + (cq1 << 10) + h;
    const float* b2 = etab + (cq2 << 10) + h;

    // pass 1: gather rows into registers, accumulate denominators
    float r0[LW], r1[LW], r2[LW];
    float d0 = 0.f, d1 = 0.f, d2 = 0.f;
    #pragma unroll
    for (int kp = 0; kp < LW; ++kp) {
      int o = __shfl(c_l, kp) << 3;
      r0[kp] = b0[o]; r1[kp] = b1[o]; r2[kp] = b2[o];
      d0 += r0[kp]; d1 += r1[kp]; d2 += r2[kp];
    }
    float i0 = cq0 ? invc / d0 : 0.f;
    float i1 = cq1 ? invc / d1 : 0.f;
    float i2 = cq2 ? invc / d2 : 0.f;

    // pass 2: register-only weighting, q-reduce, scatter to char bins
    #pragma unroll
    for (int kp = 0; kp < LW; ++kp) {
      int ck = __shfl(c_l, kp);   // wave-uniform
      if (ck) {
        float v = r0[kp] * i0 + r1[kp] * i1 + r2[kp] * i2;
        v += __shfl_xor(v, 8);
        v += __shfl_xor(v, 16);
        v += __shfl_xor(v, 32);
        if (qg == 0) atomicAdd(&bins[(ck << 3) + h], v);
      }
    }
  }
  __syncthreads();

  // write Wn[g][h][c] from bins[c][h]
  const float invn = nw ? 1.f / (float)nw : 0.f;
  for (int i = t; i < NH * VOC; i += 256) {
    int hh = i >> 7, cc = i & 127;
    Wn[(size_t)g * 1024 + i] = bins[(cc << 3) + hh] * invn;
  }
}

extern "C" void kernel_launch(void* const* d_in, const int* in_sizes, int n_in,
                              void* d_out, int out_size, void* d_ws, size_t ws_size,
                              hipStream_t stream) {
  const int*   inputs  = (const int*)d_in[0];
  const int*   n_words = (const int*)d_in[1];
  const float* emb     = (const float*)d_in[3];
  const float* Wq      = (const float*)d_in[4];
  const float* Wk      = (const float*)d_in[5];
  const float* Wv      = (const float*)d_in[6];
  const float* Wo      = (const float*)d_in[7];
  const float* W1      = (const float*)d_in[8];
  const float* W2      = (const float*)d_in[9];
  float* out = (float*)d_out;

  // workspace layout (floats), ~40 MB (d_ws is 256 MB per poison-fill size)
  float* ws   = (float*)d_ws;
  float* ES   = ws;                     // 458752: [EQ|EK|EV|WF]
  float* BIG  = ws + 458752;            // 4194304: stage1 partials, then NP@WF partials
  float* TAB  = ws + 4653056;           // 131072: exp table [c1][c2][h]
  float* NP   = ws + 4784128;           // 2048*512
  float* Wn   = ws + 5832704;           // 2048*1024 = 2097152
  float* OUTP = ws + 7929856;           // 4 x 2048*256 out partials

  // stage-1 fused GEMMs, split-K=4 -> 448 blocks
  k_stage1<4><<<dim3(112, 4), 256, 0, stream>>>(emb, Wq, Wk, Wv, Wo, W1, BIG);
  k_reduce<0, 4><<<S1_LEN / 4 / 256, 256, 0, stream>>>(BIG, ES, S1_LEN / 4, S1_LEN / 4);
  // exp(qk) table from EQ, EK (pad rows/cols zeroed)
  k_qk_tab<<<dim3(VOC, NH), 128, 0, stream>>>(ES, ES + 65536, TAB);
  // fused offsets + histogram -> Wn
  k_bins<<<GNAMES, 256, 0, stream>>>(inputs, n_words, TAB, Wn);
  // NP = per-head Wn @ EV (tiled GEMM, EV reuse through LDS)
  k_npool<<<dim3(GNAMES / 64, NH), 256, 0, stream>>>(Wn, ES + 131072, NP);
  // NP @ WF, split-K=4 -> partials in BIG (stage1 partials dead by now)
  k_gemm64<0><<<dim3(8, 32, 4), 256, 0, stream>>>(NP, ES + 196608, BIG, 2048, 512, 512, 128);
  // out_partials = tanh(sum BIG partials) @ W2, split-K=4
  k_gemm_tail<<<dim3(4, 32, 4), 256, 0, stream>>>(BIG, W2, OUTP, 128);
  // out = tanh(sum out_partials)
  k_reduce<1, 4><<<(GNAMES * F2) / 4 / 256, 256, 0, stream>>>(OUTP, out, (GNAMES * F2) / 4, (GNAMES * F2) / 4);
}